// Round 4
// baseline (12875.533 us; speedup 1.0000x reference)
//
#include <hip/hip_runtime.h>
#include <hip/hip_bf16.h>

typedef __hip_bfloat16 bf16;

#define BATCH 8
#define SEQ   1568            // 14*14*8 tokens per batch
#define M_TOK (BATCH*SEQ)     // 12544
#define DM    768
#define DI    1536
#define DS    16
#define DTR   48
#define NCLS  1000
#define LAYERS 4

__device__ __forceinline__ float b2f(bf16 v){ return __bfloat162float(v); }
__device__ __forceinline__ bf16  f2b(float v){ return __float2bfloat16(v); }

// ---------------------------------------------------------------- dtype probe
// norm_w is all ones. bf16 storage: first u16 = 0x3F80. fp32 storage: first u16 = 0x0000.
__global__ void detect_dtype(const unsigned short* __restrict__ probe, unsigned* __restrict__ flag)
{
    if (threadIdx.x == 0 && blockIdx.x == 0) flag[0] = (probe[0] == 0) ? 1u : 0u;  // 1 = fp32
}

__global__ __launch_bounds__(256)
void to_bf16(const unsigned* __restrict__ flag, const void* __restrict__ src,
             bf16* __restrict__ dst, int n)
{
    int i = blockIdx.x*256 + threadIdx.x;
    if (i >= n) return;
    dst[i] = flag[0] ? f2b(((const float*)src)[i]) : ((const bf16*)src)[i];
}

__global__ __launch_bounds__(256)
void to_f32(const unsigned* __restrict__ flag, const void* __restrict__ src,
            float* __restrict__ dst, int n)
{
    int i = blockIdx.x*256 + threadIdx.x;
    if (i >= n) return;
    dst[i] = flag[0] ? ((const float*)src)[i] : b2f(((const bf16*)src)[i]);
}

// ---------------------------------------------------------------- gather patches (per batch-group)
__global__ __launch_bounds__(256)
void gather_patches(const bf16* __restrict__ x, bf16* __restrict__ Ap, int b0)
{
    size_t idx = (size_t)blockIdx.x*256 + threadIdx.x;
    int i = (int)(idx & 255);
    int m = (int)(idx >> 8);                    // local token row
    int b = b0 + m / SEQ, s = m % SEQ;
    int hw = s >> 3, c = s & 7;
    int h = hw / 14, w = hw % 14;
    int p = i >> 4, q = i & 15;
    Ap[idx] = x[(((size_t)(b*8 + c)*224) + h*16 + p)*224 + w*16 + q];
}

// ---------------------------------------------------------------- generic GEMM
// C[m,n] = sum_k A[m,k] * W[n,k]  (A,W bf16 row-major; bias/chan fp32)
// epi 0: Cb = bf16(acc)
// epi 1: Cb = bf16(softplus(acc + bias[n]))
// epi 2: Cf += acc
// epi 3: Cf = acc + bias[n] + chan[(m&7)*N + n]
__global__ __launch_bounds__(256)
void gemm_bt(const bf16* __restrict__ A, int lda,
             const bf16* __restrict__ W, int ldw,
             float* __restrict__ Cf, bf16* __restrict__ Cb, int ldc,
             const float* __restrict__ bias, const float* __restrict__ chan,
             int M, int N, int K, int epi)
{
    __shared__ float As[16][68];
    __shared__ float Ws[16][68];
    int tid = threadIdx.x;
    int m0 = blockIdx.x*64, n0 = blockIdx.y*64;
    int tx = tid & 15, ty = tid >> 4;
    int kk = tid & 15, rr = tid >> 4;
    float acc[4][4] = {{0.f}};

    for (int k0 = 0; k0 < K; k0 += 16) {   // all K multiples of 16
        #pragma unroll
        for (int r = 0; r < 4; ++r) {
            int mm = rr + r*16;
            int gm = m0 + mm, gk = k0 + kk;
            As[kk][mm] = (gm < M) ? b2f(A[(size_t)gm*lda + gk]) : 0.f;
            int gn = n0 + mm;
            Ws[kk][mm] = (gn < N) ? b2f(W[(size_t)gn*ldw + gk]) : 0.f;
        }
        __syncthreads();
        #pragma unroll
        for (int k2 = 0; k2 < 16; ++k2) {
            float a[4], bb[4];
            #pragma unroll
            for (int i = 0; i < 4; ++i) a[i]  = As[k2][ty*4+i];
            #pragma unroll
            for (int j = 0; j < 4; ++j) bb[j] = Ws[k2][tx*4+j];
            #pragma unroll
            for (int i = 0; i < 4; ++i)
                #pragma unroll
                for (int j = 0; j < 4; ++j)
                    acc[i][j] += a[i]*bb[j];
        }
        __syncthreads();
    }

    #pragma unroll
    for (int i = 0; i < 4; ++i) {
        int gm = m0 + ty*4 + i;
        if (gm >= M) continue;
        #pragma unroll
        for (int j = 0; j < 4; ++j) {
            int gn = n0 + tx*4 + j;
            if (gn >= N) continue;
            float v = acc[i][j];
            size_t off = (size_t)gm*ldc + gn;
            if (epi == 0) {
                Cb[off] = f2b(v);
            } else if (epi == 1) {
                v += bias[gn];
                v = (v > 20.f) ? v : log1pf(__expf(v));
                Cb[off] = f2b(v);
            } else if (epi == 2) {
                Cf[off] += v;
            } else {
                Cf[off] = v + bias[gn] + chan[(size_t)(gm & 7)*N + gn];
            }
        }
    }
}

// ---------------------------------------------------------------- LayerNorm 768 (fp32 in, bf16 out)
__global__ __launch_bounds__(256)
void ln768(const float* __restrict__ X, const float* __restrict__ w,
           const float* __restrict__ bb, bf16* __restrict__ out)
{
    __shared__ float red[8];
    size_t t = blockIdx.x;
    const float* x = X + t*DM;
    float v[3]; float s = 0.f, s2 = 0.f;
    #pragma unroll
    for (int r = 0; r < 3; ++r) {
        v[r] = x[threadIdx.x + 256*r];
        s += v[r]; s2 += v[r]*v[r];
    }
    #pragma unroll
    for (int o = 32; o; o >>= 1) { s += __shfl_down(s, o, 64); s2 += __shfl_down(s2, o, 64); }
    if ((threadIdx.x & 63) == 0) { red[threadIdx.x >> 6] = s; red[(threadIdx.x >> 6) + 4] = s2; }
    __syncthreads();
    s  = red[0]+red[1]+red[2]+red[3];
    s2 = red[4]+red[5]+red[6]+red[7];
    float mu  = s * (1.f/DM);
    float inv = rsqrtf(fmaxf(s2*(1.f/DM) - mu*mu, 0.f) + 1e-5f);
    #pragma unroll
    for (int r = 0; r < 3; ++r) {
        int i = threadIdx.x + 256*r;
        out[t*DM + i] = f2b((v[r]-mu)*inv*w[i] + bb[i]);
    }
}

// ---------------------------------------------------------------- causal depthwise conv (k=4) + silu
__global__ __launch_bounds__(256)
void conv_silu(const bf16* __restrict__ xh, const float* __restrict__ cw,
               const float* __restrict__ cb, bf16* __restrict__ xc)
{
    size_t idx = (size_t)blockIdx.x*256 + threadIdx.x;   // < g*SEQ*DI
    int d = (int)(idx % DI);
    int m = (int)(idx / DI);
    int b = m / SEQ, t = m % SEQ;                        // local batch
    float acc = cb[d];
    #pragma unroll
    for (int k = 0; k < 4; ++k) {
        int tt = t + k - 3;
        if (tt >= 0)
            acc += b2f(xh[(size_t)(b*SEQ + tt)*DI + d]) * cw[d*4 + k];
    }
    float sig = 1.f/(1.f + __expf(-acc));
    xc[idx] = f2b(acc*sig);
}

// ---------------------------------------------------------------- selective scan (per batch-group)
__global__ __launch_bounds__(256)
void scan_kernel(const bf16* __restrict__ dt, const bf16* __restrict__ x,
                 const bf16* __restrict__ dbc, const float* __restrict__ Alog,
                 const float* __restrict__ Dpar, bf16* __restrict__ y)
{
    __shared__ float Bs[16][DS], Cs[16][DS];
    int b = blockIdx.x / (DI/256);                       // local batch
    int d = (blockIdx.x % (DI/256))*256 + threadIdx.x;
    float A[DS], h[DS];
    #pragma unroll
    for (int n = 0; n < DS; ++n) {
        A[n] = -expf(Alog[(size_t)d*DS + n]);
        h[n] = 0.f;
    }
    float Dv = Dpar[d];
    size_t base = (size_t)b*SEQ*DI + d;

    for (int t0 = 0; t0 < SEQ; t0 += 16) {
        __syncthreads();
        #pragma unroll
        for (int r = 0; r < 2; ++r) {
            int ii = threadIdx.x + r*256;
            int j = ii >> 5, c = ii & 31;
            float v = b2f(dbc[(size_t)(b*SEQ + t0 + j)*80 + DTR + c]);
            if (c < DS) Bs[j][c] = v; else Cs[j][c-DS] = v;
        }
        __syncthreads();
        #pragma unroll 4
        for (int j = 0; j < 16; ++j) {
            size_t off = base + (size_t)(t0 + j)*DI;
            float dtv = b2f(dt[off]);
            float xv  = b2f(x[off]);
            float dtx = dtv*xv;
            float yv = 0.f;
            #pragma unroll
            for (int n = 0; n < DS; ++n) {
                h[n] = __expf(dtv*A[n])*h[n] + dtx*Bs[j][n];
                yv += h[n]*Cs[j][n];
            }
            y[off] = f2b(yv + Dv*xv);
        }
    }
}

// ---------------------------------------------------------------- LN(1536) * silu(z) gate
__global__ __launch_bounds__(256)
void gate_ln(const bf16* __restrict__ y, const bf16* __restrict__ z,
             const float* __restrict__ w, const float* __restrict__ bb,
             bf16* __restrict__ out)
{
    __shared__ float red[8];
    size_t t = blockIdx.x;
    const bf16* yy = y + t*DI;
    const bf16* zz = z + t*DI;
    float v[6]; float s = 0.f, s2 = 0.f;
    #pragma unroll
    for (int r = 0; r < 6; ++r) {
        v[r] = b2f(yy[threadIdx.x + 256*r]);
        s += v[r]; s2 += v[r]*v[r];
    }
    #pragma unroll
    for (int o = 32; o; o >>= 1) { s += __shfl_down(s, o, 64); s2 += __shfl_down(s2, o, 64); }
    if ((threadIdx.x & 63) == 0) { red[threadIdx.x >> 6] = s; red[(threadIdx.x >> 6) + 4] = s2; }
    __syncthreads();
    s  = red[0]+red[1]+red[2]+red[3];
    s2 = red[4]+red[5]+red[6]+red[7];
    float mu  = s * (1.f/DI);
    float inv = rsqrtf(fmaxf(s2*(1.f/DI) - mu*mu, 0.f) + 1e-5f);
    #pragma unroll
    for (int r = 0; r < 6; ++r) {
        int i = threadIdx.x + 256*r;
        float zv = b2f(zz[i]);
        float sig = 1.f/(1.f + __expf(-zv));
        out[t*DI + i] = f2b(((v[r]-mu)*inv*w[i] + bb[i]) * (zv*sig));
    }
}

// ---------------------------------------------------------------- mean pool over tokens
__global__ __launch_bounds__(256)
void pool_kernel(const bf16* __restrict__ hf, float* __restrict__ pooled)
{
    int idx = blockIdx.x*256 + threadIdx.x;   // < BATCH*DM
    int b = idx / DM, dm = idx % DM;
    const bf16* p = hf + (size_t)b*SEQ*DM + dm;
    float s = 0.f;
    for (int t = 0; t < SEQ; ++t) s += b2f(p[(size_t)t*DM]);
    pooled[idx] = s * (1.f/SEQ);
}

// ---------------------------------------------------------------- classifier head
// output dtype follows the detected input dtype: fp32 when flag==1, bf16 otherwise
__global__ __launch_bounds__(256)
void head_kernel(const unsigned* __restrict__ flag,
                 const float* __restrict__ pooled, const bf16* __restrict__ hw,
                 const float* __restrict__ hb, void* __restrict__ out)
{
    int idx = blockIdx.x*256 + threadIdx.x;
    if (idx >= BATCH*NCLS) return;
    int b = idx / NCLS, n = idx % NCLS;
    const float* p = pooled + b*DM;
    const bf16* w = hw + (size_t)n*DM;
    float acc = hb[n];
    for (int k = 0; k < DM; ++k) acc += p[k]*b2f(w[k]);
    if (flag[0]) ((float*)out)[idx] = acc;
    else         ((bf16*)out)[idx]  = f2b(acc);
}

// ================================================================ launcher
extern "C" void kernel_launch(void* const* d_in, const int* in_sizes, int n_in,
                              void* d_out, int out_size, void* d_ws, size_t ws_size,
                              hipStream_t stream)
{
    (void)n_in; (void)out_size;
    dim3 blk(256);

    // true -> canonicalize to fp32 (small / numerically sensitive); false -> bf16 (GEMM operands)
    const bool is_f32[21] = { false, false, true, true, true, true, false, true, true,
                              false, false, true,  true, true, true, true, false,
                              true,  true,  false, true };

    size_t off = 0;
    auto carve = [&](size_t bytes) -> void* {
        void* q = (char*)d_ws + off;
        off += (bytes + 255) & ~(size_t)255;
        return q;
    };

    unsigned* flag = (unsigned*)carve(256);
    void* canon[21];
    for (int i = 0; i < 21; ++i)
        canon[i] = carve((size_t)in_sizes[i] * (is_f32[i] ? 4 : 2));

    float* residual = (float*)carve((size_t)M_TOK*DM*4);
    bf16*  hn       = (bf16*) carve((size_t)M_TOK*DM*2);
    float* pooled   = (float*)carve((size_t)BATCH*DM*4);

    // pick batch-group size g so everything fits in ws_size
    const size_t inner1 = 4*(((size_t)SEQ*DI*2 + 255) & ~(size_t)255)
                          + (((size_t)SEQ*80*2 + 255) & ~(size_t)255);
    int g = 8;
    while (g > 1 && off + (size_t)g*inner1 > ws_size) g >>= 1;

    bf16* xh  = (bf16*)carve((size_t)g*SEQ*DI*2);   // also Ap / ybuf
    bf16* zh  = (bf16*)carve((size_t)g*SEQ*DI*2);
    bf16* xc  = (bf16*)carve((size_t)g*SEQ*DI*2);
    bf16* dtb = (bf16*)carve((size_t)g*SEQ*DI*2);   // also gated
    bf16* dbc = (bf16*)carve((size_t)g*SEQ*80*2);
    bf16* Ap    = xh;
    bf16* ybuf  = xh;
    bf16* gated = dtb;

    // ---- dtype detection + canonicalization (runs every launch; graph-safe) ----
    detect_dtype<<<1, 64, 0, stream>>>((const unsigned short*)d_in[4], flag);
    for (int i = 0; i < 21; ++i) {
        int n = in_sizes[i];
        int gr = (n + 255)/256;
        if (is_f32[i]) to_f32 <<<gr, blk, 0, stream>>>(flag, d_in[i], (float*)canon[i], n);
        else           to_bf16<<<gr, blk, 0, stream>>>(flag, d_in[i], (bf16*) canon[i], n);
    }

    const bf16*  xin   = (const bf16*) canon[0];
    const bf16*  pw    = (const bf16*) canon[1];
    const float* pb    = (const float*)canon[2];
    const float* chan  = (const float*)canon[3];
    const float* nw    = (const float*)canon[4];
    const float* nb    = (const float*)canon[5];
    const bf16*  ipw   = (const bf16*) canon[6];
    const float* cw    = (const float*)canon[7];
    const float* cb    = (const float*)canon[8];
    const bf16*  xpw   = (const bf16*) canon[9];
    const bf16*  dtw   = (const bf16*) canon[10];
    const float* dtbia = (const float*)canon[11];
    const float* Alog  = (const float*)canon[12];
    const float* Dpar  = (const float*)canon[13];
    const float* snw   = (const float*)canon[14];
    const float* snb   = (const float*)canon[15];
    const bf16*  opw   = (const bf16*) canon[16];
    const float* nfw   = (const float*)canon[17];
    const float* nfb   = (const float*)canon[18];
    const bf16*  hw    = (const bf16*) canon[19];
    const float* hb    = (const float*)canon[20];

    const int MG = g*SEQ;                 // rows per group
    const int GX = (MG + 63)/64;

    // ---- patch embed -> residual (fp32) ----
    for (int b0 = 0; b0 < BATCH; b0 += g) {
        gather_patches<<<MG, blk, 0, stream>>>(xin, Ap, b0);
        dim3 gr(GX, DM/64);
        gemm_bt<<<gr, blk, 0, stream>>>(Ap, 256, pw, 256,
                                        residual + (size_t)b0*SEQ*DM, nullptr, DM,
                                        pb, chan, MG, DM, 256, 3);
    }

    for (int l = 0; l < LAYERS; ++l) {
        ln768<<<M_TOK, blk, 0, stream>>>(residual, nw + l*DM, nb + l*DM, hn);
        for (int b0 = 0; b0 < BATCH; b0 += g) {
            const bf16* hng = hn + (size_t)b0*SEQ*DM;
            {   dim3 gr(GX, DI/64);   // in_proj x-half
                gemm_bt<<<gr, blk, 0, stream>>>(hng, DM, ipw + (size_t)l*2*DI*DM, DM,
                                                nullptr, xh, DI, nullptr, nullptr,
                                                MG, DI, DM, 0);
                // in_proj z-half
                gemm_bt<<<gr, blk, 0, stream>>>(hng, DM, ipw + (size_t)l*2*DI*DM + (size_t)DI*DM, DM,
                                                nullptr, zh, DI, nullptr, nullptr,
                                                MG, DI, DM, 0);
            }
            conv_silu<<<(MG*DI)/256, blk, 0, stream>>>(xh, cw + (size_t)l*DI*4, cb + l*DI, xc);
            {   dim3 gr(GX, 2);       // x_proj -> dbc (N=80)
                gemm_bt<<<gr, blk, 0, stream>>>(xc, DI, xpw + (size_t)l*80*DI, DI,
                                                nullptr, dbc, 80, nullptr, nullptr,
                                                MG, 80, DI, 0);
            }
            {   dim3 gr(GX, DI/64);   // dt_proj + softplus
                gemm_bt<<<gr, blk, 0, stream>>>(dbc, 80, dtw + (size_t)l*DI*DTR, DTR,
                                                nullptr, dtb, DI, dtbia + l*DI, nullptr,
                                                MG, DI, DTR, 1);
            }
            scan_kernel<<<g*(DI/256), blk, 0, stream>>>(dtb, xc, dbc,
                                                        Alog + (size_t)l*DI*DS,
                                                        Dpar + l*DI, ybuf);
            gate_ln<<<MG, blk, 0, stream>>>(ybuf, zh, snw + l*DI, snb + l*DI, gated);
            {   dim3 gr(GX, DM/64);   // out_proj += residual
                gemm_bt<<<gr, blk, 0, stream>>>(gated, DI, opw + (size_t)l*DM*DI, DI,
                                                residual + (size_t)b0*SEQ*DM, nullptr, DM,
                                                nullptr, nullptr, MG, DM, DI, 2);
            }
        }
    }

    ln768<<<M_TOK, blk, 0, stream>>>(residual, nfw, nfb, hn);
    pool_kernel<<<(BATCH*DM)/256, blk, 0, stream>>>(hn, pooled);
    head_kernel<<<(BATCH*NCLS + 255)/256, blk, 0, stream>>>(flag, pooled, hw, hb, d_out);
}

// Round 5
// 4394.658 us; speedup vs baseline: 2.9298x; 2.9298x over previous
//
#include <hip/hip_runtime.h>
#include <hip/hip_bf16.h>

typedef __hip_bfloat16 bf16;
typedef __attribute__((ext_vector_type(8))) short short8;
typedef __attribute__((ext_vector_type(4))) float float4v;

#define BATCH 8
#define SEQ   1568            // 14*14*8 tokens per batch
#define M_TOK (BATCH*SEQ)     // 12544
#define DM    768
#define DI    1536
#define DS    16
#define DTR   48
#define NCLS  1000
#define LAYERS 4

__device__ __forceinline__ float b2f(bf16 v){ return __bfloat162float(v); }
__device__ __forceinline__ bf16  f2b(float v){ return __float2bfloat16(v); }

// ---------------------------------------------------------------- dtype probe
__global__ void detect_dtype(const unsigned short* __restrict__ probe, unsigned* __restrict__ flag)
{
    if (threadIdx.x == 0 && blockIdx.x == 0) flag[0] = (probe[0] == 0) ? 1u : 0u;  // 1 = fp32
}

__global__ __launch_bounds__(256)
void to_bf16(const unsigned* __restrict__ flag, const void* __restrict__ src,
             bf16* __restrict__ dst, int n)
{
    int i = blockIdx.x*256 + threadIdx.x;
    if (i >= n) return;
    dst[i] = flag[0] ? f2b(((const float*)src)[i]) : ((const bf16*)src)[i];
}

__global__ __launch_bounds__(256)
void to_f32(const unsigned* __restrict__ flag, const void* __restrict__ src,
            float* __restrict__ dst, int n)
{
    int i = blockIdx.x*256 + threadIdx.x;
    if (i >= n) return;
    dst[i] = flag[0] ? ((const float*)src)[i] : b2f(((const bf16*)src)[i]);
}

// ---------------------------------------------------------------- gather patches (per batch-group)
__global__ __launch_bounds__(256)
void gather_patches(const bf16* __restrict__ x, bf16* __restrict__ Ap, int b0)
{
    size_t idx = (size_t)blockIdx.x*256 + threadIdx.x;
    int i = (int)(idx & 255);
    int m = (int)(idx >> 8);
    int b = b0 + m / SEQ, s = m % SEQ;
    int hw = s >> 3, c = s & 7;
    int h = hw / 14, w = hw % 14;
    int p = i >> 4, q = i & 15;
    Ap[idx] = x[(((size_t)(b*8 + c)*224) + h*16 + p)*224 + w*16 + q];
}

// ---------------------------------------------------------------- MFMA GEMM (128x128 tile, BK=32)
// C[m,n] = sum_k A[m,k]*W[n,k]; A (M,K) bf16, W (N,K) bf16. N,K multiples of 128/32; M guarded.
// epi 0: Cb=bf16(acc);  epi 2: Cf+=acc;  epi 3: Cf=acc+bias[n]+chan[(m&7)*N+n]
__global__ __launch_bounds__(256)
void gemm_mfma(const bf16* __restrict__ A, int lda,
               const bf16* __restrict__ W, int ldw,
               float* __restrict__ Cf, bf16* __restrict__ Cb, int ldc,
               const float* __restrict__ bias, const float* __restrict__ chan,
               int M, int N, int K, int epi)
{
    __shared__ short As[128*40];   // 32 + 8 pad elems per row (80B stride, 16B aligned)
    __shared__ short Bs[128*40];
    int tid  = threadIdx.x;
    int m0   = blockIdx.x*128, n0 = blockIdx.y*128;
    int lane = tid & 63, wv = tid >> 6;
    int wm = (wv >> 1)*64, wn = (wv & 1)*64;
    int l15 = lane & 15, quad = lane >> 4;

    float4v acc[4][4];
    #pragma unroll
    for (int i = 0; i < 4; ++i)
        #pragma unroll
        for (int j = 0; j < 4; ++j) acc[i][j] = (float4v){0.f,0.f,0.f,0.f};

    const short8 zv = {0,0,0,0,0,0,0,0};
    for (int k0 = 0; k0 < K; k0 += 32) {
        #pragma unroll
        for (int u = 0; u < 2; ++u) {
            int c   = tid*2 + u;           // 512 chunks of 16B
            int row = c >> 2, ch = c & 3;
            short8 va = (m0 + row < M)
                ? *(const short8*)((const short*)A + (size_t)(m0+row)*lda + k0 + ch*8) : zv;
            *(short8*)(As + row*40 + ch*8) = va;
            *(short8*)(Bs + row*40 + ch*8) =
                *(const short8*)((const short*)W + (size_t)(n0+row)*ldw + k0 + ch*8);
        }
        __syncthreads();
        short8 av[4], bv[4];
        #pragma unroll
        for (int i = 0; i < 4; ++i) av[i] = *(const short8*)(As + (wm + i*16 + l15)*40 + quad*8);
        #pragma unroll
        for (int j = 0; j < 4; ++j) bv[j] = *(const short8*)(Bs + (wn + j*16 + l15)*40 + quad*8);
        #pragma unroll
        for (int i = 0; i < 4; ++i)
            #pragma unroll
            for (int j = 0; j < 4; ++j)
                acc[i][j] = __builtin_amdgcn_mfma_f32_16x16x32_bf16(av[i], bv[j], acc[i][j], 0, 0, 0);
        __syncthreads();
    }

    // C/D layout: col = lane&15, row = quad*4 + reg   [m89-verified]
    #pragma unroll
    for (int i = 0; i < 4; ++i) {
        #pragma unroll
        for (int j = 0; j < 4; ++j) {
            int gn = n0 + wn + j*16 + l15;
            #pragma unroll
            for (int r = 0; r < 4; ++r) {
                int gm = m0 + wm + i*16 + quad*4 + r;
                if (gm >= M) continue;
                float v = acc[i][j][r];
                size_t off = (size_t)gm*ldc + gn;
                if (epi == 0)      Cb[off] = f2b(v);
                else if (epi == 2) Cf[off] += v;
                else               Cf[off] = v + bias[gn] + chan[(size_t)(gm & 7)*N + gn];
            }
        }
    }
}

// ---------------------------------------------------------------- VALU GEMM (small shapes: N=80, K=48)
// epi 0: Cb=bf16(acc);  epi 1: Cb=bf16(softplus(acc+bias[n]))
__global__ __launch_bounds__(256)
void gemm_bt(const bf16* __restrict__ A, int lda,
             const bf16* __restrict__ W, int ldw,
             bf16* __restrict__ Cb, int ldc,
             const float* __restrict__ bias,
             int M, int N, int K, int epi)
{
    __shared__ float As[16][68];
    __shared__ float Ws[16][68];
    int tid = threadIdx.x;
    int m0 = blockIdx.x*64, n0 = blockIdx.y*64;
    int tx = tid & 15, ty = tid >> 4;
    int kk = tid & 15, rr = tid >> 4;
    float acc[4][4] = {{0.f}};

    for (int k0 = 0; k0 < K; k0 += 16) {
        #pragma unroll
        for (int r = 0; r < 4; ++r) {
            int mm = rr + r*16;
            int gm = m0 + mm, gk = k0 + kk;
            As[kk][mm] = (gm < M) ? b2f(A[(size_t)gm*lda + gk]) : 0.f;
            int gn = n0 + mm;
            Ws[kk][mm] = (gn < N) ? b2f(W[(size_t)gn*ldw + gk]) : 0.f;
        }
        __syncthreads();
        #pragma unroll
        for (int k2 = 0; k2 < 16; ++k2) {
            float a[4], bb[4];
            #pragma unroll
            for (int i = 0; i < 4; ++i) a[i]  = As[k2][ty*4+i];
            #pragma unroll
            for (int j = 0; j < 4; ++j) bb[j] = Ws[k2][tx*4+j];
            #pragma unroll
            for (int i = 0; i < 4; ++i)
                #pragma unroll
                for (int j = 0; j < 4; ++j)
                    acc[i][j] += a[i]*bb[j];
        }
        __syncthreads();
    }

    #pragma unroll
    for (int i = 0; i < 4; ++i) {
        int gm = m0 + ty*4 + i;
        if (gm >= M) continue;
        #pragma unroll
        for (int j = 0; j < 4; ++j) {
            int gn = n0 + tx*4 + j;
            if (gn >= N) continue;
            float v = acc[i][j];
            size_t off = (size_t)gm*ldc + gn;
            if (epi == 0) {
                Cb[off] = f2b(v);
            } else {
                v += bias[gn];
                v = (v > 20.f) ? v : log1pf(__expf(v));
                Cb[off] = f2b(v);
            }
        }
    }
}

// ---------------------------------------------------------------- LayerNorm 768 (fp32 in, bf16 out)
__global__ __launch_bounds__(256)
void ln768(const float* __restrict__ X, const float* __restrict__ w,
           const float* __restrict__ bb, bf16* __restrict__ out)
{
    __shared__ float red[8];
    size_t t = blockIdx.x;
    const float* x = X + t*DM;
    float v[3]; float s = 0.f, s2 = 0.f;
    #pragma unroll
    for (int r = 0; r < 3; ++r) {
        v[r] = x[threadIdx.x + 256*r];
        s += v[r]; s2 += v[r]*v[r];
    }
    #pragma unroll
    for (int o = 32; o; o >>= 1) { s += __shfl_down(s, o, 64); s2 += __shfl_down(s2, o, 64); }
    if ((threadIdx.x & 63) == 0) { red[threadIdx.x >> 6] = s; red[(threadIdx.x >> 6) + 4] = s2; }
    __syncthreads();
    s  = red[0]+red[1]+red[2]+red[3];
    s2 = red[4]+red[5]+red[6]+red[7];
    float mu  = s * (1.f/DM);
    float inv = rsqrtf(fmaxf(s2*(1.f/DM) - mu*mu, 0.f) + 1e-5f);
    #pragma unroll
    for (int r = 0; r < 3; ++r) {
        int i = threadIdx.x + 256*r;
        out[t*DM + i] = f2b((v[r]-mu)*inv*w[i] + bb[i]);
    }
}

// ---------------------------------------------------------------- causal depthwise conv (k=4) + silu
__global__ __launch_bounds__(256)
void conv_silu(const bf16* __restrict__ xh, const float* __restrict__ cw,
               const float* __restrict__ cb, bf16* __restrict__ xc)
{
    size_t idx = (size_t)blockIdx.x*256 + threadIdx.x;   // < g*SEQ*DI
    int d = (int)(idx % DI);
    int m = (int)(idx / DI);
    int b = m / SEQ, t = m % SEQ;                        // local batch
    float acc = cb[d];
    #pragma unroll
    for (int k = 0; k < 4; ++k) {
        int tt = t + k - 3;
        if (tt >= 0)
            acc += b2f(xh[(size_t)(b*SEQ + tt)*DI + d]) * cw[d*4 + k];
    }
    float sig = 1.f/(1.f + __expf(-acc));
    xc[idx] = f2b(acc*sig);
}

// ---------------------------------------------------------------- selective scan v2
// one LANE per (b, d, n): h is a scalar register; y reduced over the 16 n-lanes
// block = 256 threads = 16 d-chains x 16 states, one b; grid = g * (DI/16)
__global__ __launch_bounds__(256)
void scan_kernel(const bf16* __restrict__ dt, const bf16* __restrict__ x,
                 const bf16* __restrict__ dbc, const float* __restrict__ Alog,
                 const float* __restrict__ Dpar, bf16* __restrict__ y)
{
    __shared__ float dts[16][16], xs[16][16], Bsh[16][16], Csh[16][16];
    __shared__ bf16  ys[16][16];

    int b  = blockIdx.x / (DI/16);
    int d0 = (blockIdx.x % (DI/16)) * 16;
    int tid = threadIdx.x;
    int n  = tid & 15;          // state index (lane group)
    int dl = tid >> 4;          // local d-chain 0..15
    int d  = d0 + dl;

    // A2 = -exp(Alog)*log2(e): dA = exp2(dtv*A2)
    float A2 = -__expf(Alog[(size_t)d*DS + n]) * 1.44269504f;
    float Dv = Dpar[d];
    float h = 0.f;

    int tl = tid >> 4, il = tid & 15;   // staging coords: (timestep, inner)

    for (int t0 = 0; t0 < SEQ; t0 += 16) {
        __syncthreads();
        {
            size_t rowm = (size_t)(b*SEQ + t0 + tl);
            dts[tl][il] = b2f(dt [rowm*DI + d0 + il]);
            xs [tl][il] = b2f(x  [rowm*DI + d0 + il]);
            Bsh[tl][il] = b2f(dbc[rowm*80 + DTR + il]);
            Csh[tl][il] = b2f(dbc[rowm*80 + DTR + DS + il]);
        }
        __syncthreads();
        #pragma unroll
        for (int j = 0; j < 16; ++j) {
            float dtv = dts[j][dl];
            float xv  = xs [j][dl];
            h = exp2f(dtv*A2)*h + (dtv*xv)*Bsh[j][n];
            float p = h*Csh[j][n];
            #pragma unroll
            for (int o = 1; o < 16; o <<= 1) p += __shfl_xor(p, o, 16);
            if (n == 0) ys[j][dl] = f2b(p + Dv*xv);
        }
        __syncthreads();
        y[(size_t)(b*SEQ + t0 + tl)*DI + d0 + il] = ys[tl][il];
    }
}

// ---------------------------------------------------------------- LN(1536) * silu(z) gate
__global__ __launch_bounds__(256)
void gate_ln(const bf16* __restrict__ y, const bf16* __restrict__ z,
             const float* __restrict__ w, const float* __restrict__ bb,
             bf16* __restrict__ out)
{
    __shared__ float red[8];
    size_t t = blockIdx.x;
    const bf16* yy = y + t*DI;
    const bf16* zz = z + t*DI;
    float v[6]; float s = 0.f, s2 = 0.f;
    #pragma unroll
    for (int r = 0; r < 6; ++r) {
        v[r] = b2f(yy[threadIdx.x + 256*r]);
        s += v[r]; s2 += v[r]*v[r];
    }
    #pragma unroll
    for (int o = 32; o; o >>= 1) { s += __shfl_down(s, o, 64); s2 += __shfl_down(s2, o, 64); }
    if ((threadIdx.x & 63) == 0) { red[threadIdx.x >> 6] = s; red[(threadIdx.x >> 6) + 4] = s2; }
    __syncthreads();
    s  = red[0]+red[1]+red[2]+red[3];
    s2 = red[4]+red[5]+red[6]+red[7];
    float mu  = s * (1.f/DI);
    float inv = rsqrtf(fmaxf(s2*(1.f/DI) - mu*mu, 0.f) + 1e-5f);
    #pragma unroll
    for (int r = 0; r < 6; ++r) {
        int i = threadIdx.x + 256*r;
        float zv = b2f(zz[i]);
        float sig = 1.f/(1.f + __expf(-zv));
        out[t*DI + i] = f2b(((v[r]-mu)*inv*w[i] + bb[i]) * (zv*sig));
    }
}

// ---------------------------------------------------------------- mean pool over tokens
__global__ __launch_bounds__(256)
void pool_kernel(const bf16* __restrict__ hf, float* __restrict__ pooled)
{
    int idx = blockIdx.x*256 + threadIdx.x;   // < BATCH*DM
    int b = idx / DM, dm = idx % DM;
    const bf16* p = hf + (size_t)b*SEQ*DM + dm;
    float s = 0.f;
    for (int t = 0; t < SEQ; ++t) s += b2f(p[(size_t)t*DM]);
    pooled[idx] = s * (1.f/SEQ);
}

// ---------------------------------------------------------------- classifier head
__global__ __launch_bounds__(256)
void head_kernel(const unsigned* __restrict__ flag,
                 const float* __restrict__ pooled, const bf16* __restrict__ hw,
                 const float* __restrict__ hb, void* __restrict__ out)
{
    int idx = blockIdx.x*256 + threadIdx.x;
    if (idx >= BATCH*NCLS) return;
    int b = idx / NCLS, n = idx % NCLS;
    const float* p = pooled + b*DM;
    const bf16* w = hw + (size_t)n*DM;
    float acc = hb[n];
    for (int k = 0; k < DM; ++k) acc += p[k]*b2f(w[k]);
    if (flag[0]) ((float*)out)[idx] = acc;
    else         ((bf16*)out)[idx]  = f2b(acc);
}

// ================================================================ launcher
extern "C" void kernel_launch(void* const* d_in, const int* in_sizes, int n_in,
                              void* d_out, int out_size, void* d_ws, size_t ws_size,
                              hipStream_t stream)
{
    (void)n_in; (void)out_size;
    dim3 blk(256);

    const bool is_f32[21] = { false, false, true, true, true, true, false, true, true,
                              false, false, true,  true, true, true, true, false,
                              true,  true,  false, true };

    size_t off = 0;
    auto carve = [&](size_t bytes) -> void* {
        void* q = (char*)d_ws + off;
        off += (bytes + 255) & ~(size_t)255;
        return q;
    };

    unsigned* flag = (unsigned*)carve(256);
    void* canon[21];
    for (int i = 0; i < 21; ++i)
        canon[i] = carve((size_t)in_sizes[i] * (is_f32[i] ? 4 : 2));

    float* residual = (float*)carve((size_t)M_TOK*DM*4);
    bf16*  hn       = (bf16*) carve((size_t)M_TOK*DM*2);
    float* pooled   = (float*)carve((size_t)BATCH*DM*4);

    const size_t inner1 = 4*(((size_t)SEQ*DI*2 + 255) & ~(size_t)255)
                          + (((size_t)SEQ*80*2 + 255) & ~(size_t)255);
    int g = 8;
    while (g > 1 && off + (size_t)g*inner1 > ws_size) g >>= 1;

    bf16* xh  = (bf16*)carve((size_t)g*SEQ*DI*2);   // also Ap / ybuf
    bf16* zh  = (bf16*)carve((size_t)g*SEQ*DI*2);
    bf16* xc  = (bf16*)carve((size_t)g*SEQ*DI*2);
    bf16* dtb = (bf16*)carve((size_t)g*SEQ*DI*2);   // also gated
    bf16* dbc = (bf16*)carve((size_t)g*SEQ*80*2);
    bf16* Ap    = xh;
    bf16* ybuf  = xh;
    bf16* gated = dtb;

    detect_dtype<<<1, 64, 0, stream>>>((const unsigned short*)d_in[4], flag);
    for (int i = 0; i < 21; ++i) {
        int n = in_sizes[i];
        int gr = (n + 255)/256;
        if (is_f32[i]) to_f32 <<<gr, blk, 0, stream>>>(flag, d_in[i], (float*)canon[i], n);
        else           to_bf16<<<gr, blk, 0, stream>>>(flag, d_in[i], (bf16*) canon[i], n);
    }

    const bf16*  xin   = (const bf16*) canon[0];
    const bf16*  pw    = (const bf16*) canon[1];
    const float* pb    = (const float*)canon[2];
    const float* chan  = (const float*)canon[3];
    const float* nw    = (const float*)canon[4];
    const float* nb    = (const float*)canon[5];
    const bf16*  ipw   = (const bf16*) canon[6];
    const float* cw    = (const float*)canon[7];
    const float* cb    = (const float*)canon[8];
    const bf16*  xpw   = (const bf16*) canon[9];
    const bf16*  dtw   = (const bf16*) canon[10];
    const float* dtbia = (const float*)canon[11];
    const float* Alog  = (const float*)canon[12];
    const float* Dpar  = (const float*)canon[13];
    const float* snw   = (const float*)canon[14];
    const float* snb   = (const float*)canon[15];
    const bf16*  opw   = (const bf16*) canon[16];
    const float* nfw   = (const float*)canon[17];
    const float* nfb   = (const float*)canon[18];
    const bf16*  hw    = (const bf16*) canon[19];
    const float* hb    = (const float*)canon[20];

    const int MG  = g*SEQ;
    const int GXm = (MG + 127)/128;       // MFMA grid (M)
    const int GX  = (MG + 63)/64;         // VALU grid (M)

    // ---- patch embed -> residual (fp32), MFMA epi3 ----
    for (int b0 = 0; b0 < BATCH; b0 += g) {
        gather_patches<<<MG, blk, 0, stream>>>(xin, Ap, b0);
        dim3 gr(GXm, DM/128);
        gemm_mfma<<<gr, blk, 0, stream>>>(Ap, 256, pw, 256,
                                          residual + (size_t)b0*SEQ*DM, nullptr, DM,
                                          pb, chan, MG, DM, 256, 3);
    }

    for (int l = 0; l < LAYERS; ++l) {
        ln768<<<M_TOK, blk, 0, stream>>>(residual, nw + l*DM, nb + l*DM, hn);
        for (int b0 = 0; b0 < BATCH; b0 += g) {
            const bf16* hng = hn + (size_t)b0*SEQ*DM;
            {   dim3 gr(GXm, DI/128);   // in_proj halves (MFMA)
                gemm_mfma<<<gr, blk, 0, stream>>>(hng, DM, ipw + (size_t)l*2*DI*DM, DM,
                                                  nullptr, xh, DI, nullptr, nullptr,
                                                  MG, DI, DM, 0);
                gemm_mfma<<<gr, blk, 0, stream>>>(hng, DM, ipw + (size_t)l*2*DI*DM + (size_t)DI*DM, DM,
                                                  nullptr, zh, DI, nullptr, nullptr,
                                                  MG, DI, DM, 0);
            }
            conv_silu<<<(MG*DI)/256, blk, 0, stream>>>(xh, cw + (size_t)l*DI*4, cb + l*DI, xc);
            {   dim3 gr(GX, 2);         // x_proj (VALU, N=80)
                gemm_bt<<<gr, blk, 0, stream>>>(xc, DI, xpw + (size_t)l*80*DI, DI,
                                                dbc, 80, nullptr, MG, 80, DI, 0);
            }
            {   dim3 gr(GX, DI/64);     // dt_proj + softplus (VALU, K=48)
                gemm_bt<<<gr, blk, 0, stream>>>(dbc, 80, dtw + (size_t)l*DI*DTR, DTR,
                                                dtb, DI, dtbia + l*DI, MG, DI, DTR, 1);
            }
            scan_kernel<<<g*(DI/16), blk, 0, stream>>>(dtb, xc, dbc,
                                                       Alog + (size_t)l*DI*DS,
                                                       Dpar + l*DI, ybuf);
            gate_ln<<<MG, blk, 0, stream>>>(ybuf, zh, snw + l*DI, snb + l*DI, gated);
            {   dim3 gr(GXm, DM/128);   // out_proj += residual (MFMA epi2)
                gemm_mfma<<<gr, blk, 0, stream>>>(gated, DI, opw + (size_t)l*DM*DI, DI,
                                                  residual + (size_t)b0*SEQ*DM, nullptr, DM,
                                                  nullptr, nullptr, MG, DM, DI, 2);
            }
        }
    }

    ln768<<<M_TOK, blk, 0, stream>>>(residual, nfw, nfb, hn);
    pool_kernel<<<(BATCH*DM)/256, blk, 0, stream>>>(hn, pooled);
    head_kernel<<<(BATCH*NCLS + 255)/256, blk, 0, stream>>>(flag, pooled, hw, hb, d_out);
}

// Round 6
// 4074.589 us; speedup vs baseline: 3.1600x; 1.0786x over previous
//
#include <hip/hip_runtime.h>
#include <hip/hip_bf16.h>

typedef __hip_bfloat16 bf16;
typedef __attribute__((ext_vector_type(8))) short short8;
typedef __attribute__((ext_vector_type(4))) float float4v;

#define BATCH 8
#define SEQ   1568            // 14*14*8 tokens per batch
#define M_TOK (BATCH*SEQ)     // 12544
#define DM    768
#define DI    1536
#define DS    16
#define DTR   48
#define NCLS  1000
#define LAYERS 4

__device__ __forceinline__ float b2f(bf16 v){ return __bfloat162float(v); }
__device__ __forceinline__ bf16  f2b(float v){ return __float2bfloat16(v); }
__device__ __forceinline__ float us2f(unsigned short u){
    unsigned v = ((unsigned)u) << 16; float f; __builtin_memcpy(&f, &v, 4); return f;
}

// ---------------------------------------------------------------- dtype probe
__global__ void detect_dtype(const unsigned short* __restrict__ probe, unsigned* __restrict__ flag)
{
    if (threadIdx.x == 0 && blockIdx.x == 0) flag[0] = (probe[0] == 0) ? 1u : 0u;  // 1 = fp32
}

__global__ __launch_bounds__(256)
void to_bf16(const unsigned* __restrict__ flag, const void* __restrict__ src,
             bf16* __restrict__ dst, int n)
{
    int i = blockIdx.x*256 + threadIdx.x;
    if (i >= n) return;
    dst[i] = flag[0] ? f2b(((const float*)src)[i]) : ((const bf16*)src)[i];
}

__global__ __launch_bounds__(256)
void to_f32(const unsigned* __restrict__ flag, const void* __restrict__ src,
            float* __restrict__ dst, int n)
{
    int i = blockIdx.x*256 + threadIdx.x;
    if (i >= n) return;
    dst[i] = flag[0] ? ((const float*)src)[i] : b2f(((const bf16*)src)[i]);
}

// ---------------------------------------------------------------- gather patches (per batch-group)
__global__ __launch_bounds__(256)
void gather_patches(const bf16* __restrict__ x, bf16* __restrict__ Ap, int b0)
{
    size_t idx = (size_t)blockIdx.x*256 + threadIdx.x;
    int i = (int)(idx & 255);
    int m = (int)(idx >> 8);
    int b = b0 + m / SEQ, s = m % SEQ;
    int hw = s >> 3, c = s & 7;
    int h = hw / 14, w = hw % 14;
    int p = i >> 4, q = i & 15;
    Ap[idx] = x[(((size_t)(b*8 + c)*224) + h*16 + p)*224 + w*16 + q];
}

// ---------------------------------------------------------------- MFMA GEMM (128x128 tile, BK=32)
// C[m,n] = sum_k A[m,k]*W[n,k]; A (M,K) bf16 lda, W (N,K) bf16 ldw.
// Guards: M per-row, N per-row+store, K at 8-element chunk granularity (zero fill).
// epi 0: Cb=bf16(acc); epi 1: Cb=bf16(softplus(acc+bias[n])); epi 2: Cf+=acc;
// epi 3: Cf=acc+bias[n]+chan[(m&7)*N+n]
__global__ __launch_bounds__(256)
void gemm_mfma(const bf16* __restrict__ A, int lda,
               const bf16* __restrict__ W, int ldw,
               float* __restrict__ Cf, bf16* __restrict__ Cb, int ldc,
               const float* __restrict__ bias, const float* __restrict__ chan,
               int M, int N, int K, int epi)
{
    __shared__ short As[128*40];   // 32 + 8 pad elems per row (80B stride, 16B aligned)
    __shared__ short Bs[128*40];
    int tid  = threadIdx.x;
    int m0   = blockIdx.x*128, n0 = blockIdx.y*128;
    int lane = tid & 63, wv = tid >> 6;
    int wm = (wv >> 1)*64, wn = (wv & 1)*64;
    int l15 = lane & 15, quad = lane >> 4;

    float4v acc[4][4];
    #pragma unroll
    for (int i = 0; i < 4; ++i)
        #pragma unroll
        for (int j = 0; j < 4; ++j) acc[i][j] = (float4v){0.f,0.f,0.f,0.f};

    const short8 zv8 = {0,0,0,0,0,0,0,0};
    for (int k0 = 0; k0 < K; k0 += 32) {
        #pragma unroll
        for (int u = 0; u < 2; ++u) {
            int c   = tid*2 + u;           // 512 chunks of 16B
            int row = c >> 2, ch = c & 3;
            bool kok = (k0 + ch*8 + 8) <= K;   // K is a multiple of 8
            short8 va = (kok && m0 + row < M)
                ? *(const short8*)((const short*)A + (size_t)(m0+row)*lda + k0 + ch*8) : zv8;
            *(short8*)(As + row*40 + ch*8) = va;
            short8 vb = (kok && n0 + row < N)
                ? *(const short8*)((const short*)W + (size_t)(n0+row)*ldw + k0 + ch*8) : zv8;
            *(short8*)(Bs + row*40 + ch*8) = vb;
        }
        __syncthreads();
        short8 av[4], bv[4];
        #pragma unroll
        for (int i = 0; i < 4; ++i) av[i] = *(const short8*)(As + (wm + i*16 + l15)*40 + quad*8);
        #pragma unroll
        for (int j = 0; j < 4; ++j) bv[j] = *(const short8*)(Bs + (wn + j*16 + l15)*40 + quad*8);
        #pragma unroll
        for (int i = 0; i < 4; ++i)
            #pragma unroll
            for (int j = 0; j < 4; ++j)
                acc[i][j] = __builtin_amdgcn_mfma_f32_16x16x32_bf16(av[i], bv[j], acc[i][j], 0, 0, 0);
        __syncthreads();
    }

    // C/D layout: col = lane&15, row = quad*4 + reg
    #pragma unroll
    for (int i = 0; i < 4; ++i) {
        #pragma unroll
        for (int j = 0; j < 4; ++j) {
            int gn = n0 + wn + j*16 + l15;
            if (gn >= N) continue;
            #pragma unroll
            for (int r = 0; r < 4; ++r) {
                int gm = m0 + wm + i*16 + quad*4 + r;
                if (gm >= M) continue;
                float v = acc[i][j][r];
                size_t off = (size_t)gm*ldc + gn;
                if (epi == 0)      Cb[off] = f2b(v);
                else if (epi == 1) {
                    v += bias[gn];
                    v = (v > 20.f) ? v : log1pf(__expf(v));
                    Cb[off] = f2b(v);
                }
                else if (epi == 2) Cf[off] += v;
                else               Cf[off] = v + bias[gn] + chan[(size_t)(gm & 7)*N + gn];
            }
        }
    }
}

// ---------------------------------------------------------------- LayerNorm 768 (fp32 in, bf16 out)
__global__ __launch_bounds__(256)
void ln768(const float* __restrict__ X, const float* __restrict__ w,
           const float* __restrict__ bb, bf16* __restrict__ out)
{
    __shared__ float red[8];
    size_t t = blockIdx.x;
    const float* x = X + t*DM;
    float v[3]; float s = 0.f, s2 = 0.f;
    #pragma unroll
    for (int r = 0; r < 3; ++r) {
        v[r] = x[threadIdx.x + 256*r];
        s += v[r]; s2 += v[r]*v[r];
    }
    #pragma unroll
    for (int o = 32; o; o >>= 1) { s += __shfl_down(s, o, 64); s2 += __shfl_down(s2, o, 64); }
    if ((threadIdx.x & 63) == 0) { red[threadIdx.x >> 6] = s; red[(threadIdx.x >> 6) + 4] = s2; }
    __syncthreads();
    s  = red[0]+red[1]+red[2]+red[3];
    s2 = red[4]+red[5]+red[6]+red[7];
    float mu  = s * (1.f/DM);
    float inv = rsqrtf(fmaxf(s2*(1.f/DM) - mu*mu, 0.f) + 1e-5f);
    #pragma unroll
    for (int r = 0; r < 3; ++r) {
        int i = threadIdx.x + 256*r;
        out[t*DM + i] = f2b((v[r]-mu)*inv*w[i] + bb[i]);
    }
}

// ---------------------------------------------------------------- causal depthwise conv (k=4) + silu
__global__ __launch_bounds__(256)
void conv_silu(const bf16* __restrict__ xh, const float* __restrict__ cw,
               const float* __restrict__ cb, bf16* __restrict__ xc)
{
    size_t idx = (size_t)blockIdx.x*256 + threadIdx.x;   // < g*SEQ*DI
    int d = (int)(idx % DI);
    int m = (int)(idx / DI);
    int b = m / SEQ, t = m % SEQ;                        // local batch
    float acc = cb[d];
    #pragma unroll
    for (int k = 0; k < 4; ++k) {
        int tt = t + k - 3;
        if (tt >= 0)
            acc += b2f(xh[(size_t)(b*SEQ + tt)*DI + d]) * cw[d*4 + k];
    }
    float sig = 1.f/(1.f + __expf(-acc));
    xc[idx] = f2b(acc*sig);
}

// ---------------------------------------------------------------- selective scan v3
// 64-thread blocks: 16 d-chains x 4 state-quads (4 states per lane, h[4] in regs).
// B/C read as ds_read_b128; y-reduction = 2 shfl_xor(width 4). DS-pipe ops/step ~5 vs 8.
// grid = g * (DI/16) = 768 blocks -> 3 blocks/CU, all CUs busy.
__global__ __launch_bounds__(64)
void scan_kernel(const bf16* __restrict__ dt, const bf16* __restrict__ x,
                 const bf16* __restrict__ dbc, const float* __restrict__ Alog,
                 const float* __restrict__ Dpar, bf16* __restrict__ y)
{
    __shared__ float dts[16][16], xs[16][16], Bsh[16][16], Csh[16][16];
    __shared__ bf16  ys[16][16];

    int b  = blockIdx.x / (DI/16);
    int d0 = (blockIdx.x % (DI/16)) * 16;
    int tid = threadIdx.x;
    int s  = tid & 3;        // state quad: states s*4 .. s*4+3
    int dl = tid >> 2;       // local d-chain 0..15
    int d  = d0 + dl;

    float A2[4], h[4];
    #pragma unroll
    for (int k = 0; k < 4; ++k) {
        A2[k] = -__expf(Alog[(size_t)d*DS + s*4 + k]) * 1.44269504f;   // dA = exp2(dt*A2)
        h[k] = 0.f;
    }
    float Dv = Dpar[d];

    int st = tid >> 2;       // staging timestep 0..15
    int sd = (tid & 3) * 4;  // staging inner offset {0,4,8,12}

    for (int t0 = 0; t0 < SEQ; t0 += 16) {
        __syncthreads();
        {
            size_t rowm = (size_t)(b*SEQ + t0 + st);
            ushort4 vdt = *(const ushort4*)((const unsigned short*)dt  + rowm*DI + d0 + sd);
            ushort4 vx  = *(const ushort4*)((const unsigned short*)x   + rowm*DI + d0 + sd);
            ushort4 vB  = *(const ushort4*)((const unsigned short*)dbc + rowm*80 + DTR + sd);
            ushort4 vC  = *(const ushort4*)((const unsigned short*)dbc + rowm*80 + DTR + DS + sd);
            *(float4v*)&dts[st][sd] = (float4v){us2f(vdt.x), us2f(vdt.y), us2f(vdt.z), us2f(vdt.w)};
            *(float4v*)&xs [st][sd] = (float4v){us2f(vx.x),  us2f(vx.y),  us2f(vx.z),  us2f(vx.w)};
            *(float4v*)&Bsh[st][sd] = (float4v){us2f(vB.x),  us2f(vB.y),  us2f(vB.z),  us2f(vB.w)};
            *(float4v*)&Csh[st][sd] = (float4v){us2f(vC.x),  us2f(vC.y),  us2f(vC.z),  us2f(vC.w)};
        }
        __syncthreads();
        #pragma unroll 4
        for (int j = 0; j < 16; ++j) {
            float dtv = dts[j][dl];
            float xv  = xs [j][dl];
            float dtx = dtv * xv;
            float4v Bv = *(const float4v*)&Bsh[j][s*4];
            float4v Cv = *(const float4v*)&Csh[j][s*4];
            float p = 0.f;
            #pragma unroll
            for (int k = 0; k < 4; ++k) {
                h[k] = exp2f(dtv*A2[k])*h[k] + dtx*Bv[k];
                p += h[k]*Cv[k];
            }
            p += __shfl_xor(p, 1, 4);
            p += __shfl_xor(p, 2, 4);
            if (s == 0) ys[j][dl] = f2b(p + Dv*xv);
        }
        __syncthreads();
        {
            size_t rowm = (size_t)(b*SEQ + t0 + st);
            ushort4 vy = *(const ushort4*)((const unsigned short*)&ys[st][0] + sd);
            *(ushort4*)((unsigned short*)y + rowm*DI + d0 + sd) = vy;
        }
    }
}

// ---------------------------------------------------------------- LN(1536) * silu(z) gate
__global__ __launch_bounds__(256)
void gate_ln(const bf16* __restrict__ y, const bf16* __restrict__ z,
             const float* __restrict__ w, const float* __restrict__ bb,
             bf16* __restrict__ out)
{
    __shared__ float red[8];
    size_t t = blockIdx.x;
    const bf16* yy = y + t*DI;
    const bf16* zz = z + t*DI;
    float v[6]; float s = 0.f, s2 = 0.f;
    #pragma unroll
    for (int r = 0; r < 6; ++r) {
        v[r] = b2f(yy[threadIdx.x + 256*r]);
        s += v[r]; s2 += v[r]*v[r];
    }
    #pragma unroll
    for (int o = 32; o; o >>= 1) { s += __shfl_down(s, o, 64); s2 += __shfl_down(s2, o, 64); }
    if ((threadIdx.x & 63) == 0) { red[threadIdx.x >> 6] = s; red[(threadIdx.x >> 6) + 4] = s2; }
    __syncthreads();
    s  = red[0]+red[1]+red[2]+red[3];
    s2 = red[4]+red[5]+red[6]+red[7];
    float mu  = s * (1.f/DI);
    float inv = rsqrtf(fmaxf(s2*(1.f/DI) - mu*mu, 0.f) + 1e-5f);
    #pragma unroll
    for (int r = 0; r < 6; ++r) {
        int i = threadIdx.x + 256*r;
        float zv = b2f(zz[i]);
        float sig = 1.f/(1.f + __expf(-zv));
        out[t*DI + i] = f2b(((v[r]-mu)*inv*w[i] + bb[i]) * (zv*sig));
    }
}

// ---------------------------------------------------------------- mean pool over tokens
__global__ __launch_bounds__(256)
void pool_kernel(const bf16* __restrict__ hf, float* __restrict__ pooled)
{
    int idx = blockIdx.x*256 + threadIdx.x;   // < BATCH*DM
    int b = idx / DM, dm = idx % DM;
    const bf16* p = hf + (size_t)b*SEQ*DM + dm;
    float s = 0.f;
    for (int t = 0; t < SEQ; ++t) s += b2f(p[(size_t)t*DM]);
    pooled[idx] = s * (1.f/SEQ);
}

// ---------------------------------------------------------------- classifier head
// 8 adjacent lanes share one weight row (broadcast); ushort4 weight loads
__global__ __launch_bounds__(256)
void head_kernel(const unsigned* __restrict__ flag,
                 const float* __restrict__ pooled, const bf16* __restrict__ hw,
                 const float* __restrict__ hb, void* __restrict__ out)
{
    int idx = blockIdx.x*256 + threadIdx.x;
    if (idx >= BATCH*NCLS) return;
    int b = idx & 7, n = idx >> 3;
    const float* p = pooled + b*DM;
    const unsigned short* w = (const unsigned short*)hw + (size_t)n*DM;
    float acc = hb[n];
    for (int k = 0; k < DM; k += 4) {
        ushort4 wv = *(const ushort4*)(w + k);
        acc += p[k]*us2f(wv.x) + p[k+1]*us2f(wv.y) + p[k+2]*us2f(wv.z) + p[k+3]*us2f(wv.w);
    }
    int o = b*NCLS + n;
    if (flag[0]) ((float*)out)[o] = acc;
    else         ((bf16*)out)[o]  = f2b(acc);
}

// ================================================================ launcher
extern "C" void kernel_launch(void* const* d_in, const int* in_sizes, int n_in,
                              void* d_out, int out_size, void* d_ws, size_t ws_size,
                              hipStream_t stream)
{
    (void)n_in; (void)out_size;
    dim3 blk(256);

    const bool is_f32[21] = { false, false, true, true, true, true, false, true, true,
                              false, false, true,  true, true, true, true, false,
                              true,  true,  false, true };

    size_t off = 0;
    auto carve = [&](size_t bytes) -> void* {
        void* q = (char*)d_ws + off;
        off += (bytes + 255) & ~(size_t)255;
        return q;
    };

    unsigned* flag = (unsigned*)carve(256);
    void* canon[21];
    for (int i = 0; i < 21; ++i)
        canon[i] = carve((size_t)in_sizes[i] * (is_f32[i] ? 4 : 2));

    float* residual = (float*)carve((size_t)M_TOK*DM*4);
    bf16*  hn       = (bf16*) carve((size_t)M_TOK*DM*2);
    float* pooled   = (float*)carve((size_t)BATCH*DM*4);

    const size_t inner1 = 4*(((size_t)SEQ*DI*2 + 255) & ~(size_t)255)
                          + (((size_t)SEQ*80*2 + 255) & ~(size_t)255);
    int g = 8;
    while (g > 1 && off + (size_t)g*inner1 > ws_size) g >>= 1;

    bf16* xh  = (bf16*)carve((size_t)g*SEQ*DI*2);   // also Ap / ybuf
    bf16* zh  = (bf16*)carve((size_t)g*SEQ*DI*2);
    bf16* xc  = (bf16*)carve((size_t)g*SEQ*DI*2);
    bf16* dtb = (bf16*)carve((size_t)g*SEQ*DI*2);   // also gated
    bf16* dbc = (bf16*)carve((size_t)g*SEQ*80*2);
    bf16* Ap    = xh;
    bf16* ybuf  = xh;
    bf16* gated = dtb;

    detect_dtype<<<1, 64, 0, stream>>>((const unsigned short*)d_in[4], flag);
    for (int i = 0; i < 21; ++i) {
        int n = in_sizes[i];
        int gr = (n + 255)/256;
        if (is_f32[i]) to_f32 <<<gr, blk, 0, stream>>>(flag, d_in[i], (float*)canon[i], n);
        else           to_bf16<<<gr, blk, 0, stream>>>(flag, d_in[i], (bf16*) canon[i], n);
    }

    const bf16*  xin   = (const bf16*) canon[0];
    const bf16*  pw    = (const bf16*) canon[1];
    const float* pb    = (const float*)canon[2];
    const float* chan  = (const float*)canon[3];
    const float* nw    = (const float*)canon[4];
    const float* nb    = (const float*)canon[5];
    const bf16*  ipw   = (const bf16*) canon[6];
    const float* cw    = (const float*)canon[7];
    const float* cb    = (const float*)canon[8];
    const bf16*  xpw   = (const bf16*) canon[9];
    const bf16*  dtw   = (const bf16*) canon[10];
    const float* dtbia = (const float*)canon[11];
    const float* Alog  = (const float*)canon[12];
    const float* Dpar  = (const float*)canon[13];
    const float* snw   = (const float*)canon[14];
    const float* snb   = (const float*)canon[15];
    const bf16*  opw   = (const bf16*) canon[16];
    const float* nfw   = (const float*)canon[17];
    const float* nfb   = (const float*)canon[18];
    const bf16*  hw    = (const bf16*) canon[19];
    const float* hb    = (const float*)canon[20];

    const int MG  = g*SEQ;
    const int GXm = (MG + 127)/128;       // MFMA grid (M)

    // ---- patch embed -> residual (fp32), MFMA epi3 ----
    for (int b0 = 0; b0 < BATCH; b0 += g) {
        gather_patches<<<MG, blk, 0, stream>>>(xin, Ap, b0);
        dim3 gr(GXm, DM/128);
        gemm_mfma<<<gr, blk, 0, stream>>>(Ap, 256, pw, 256,
                                          residual + (size_t)b0*SEQ*DM, nullptr, DM,
                                          pb, chan, MG, DM, 256, 3);
    }

    for (int l = 0; l < LAYERS; ++l) {
        ln768<<<M_TOK, blk, 0, stream>>>(residual, nw + l*DM, nb + l*DM, hn);
        for (int b0 = 0; b0 < BATCH; b0 += g) {
            const bf16* hng = hn + (size_t)b0*SEQ*DM;
            {   dim3 gr(GXm, DI/128);   // in_proj halves (MFMA)
                gemm_mfma<<<gr, blk, 0, stream>>>(hng, DM, ipw + (size_t)l*2*DI*DM, DM,
                                                  nullptr, xh, DI, nullptr, nullptr,
                                                  MG, DI, DM, 0);
                gemm_mfma<<<gr, blk, 0, stream>>>(hng, DM, ipw + (size_t)l*2*DI*DM + (size_t)DI*DM, DM,
                                                  nullptr, zh, DI, nullptr, nullptr,
                                                  MG, DI, DM, 0);
            }
            conv_silu<<<(MG*DI)/256, blk, 0, stream>>>(xh, cw + (size_t)l*DI*4, cb + l*DI, xc);
            {   dim3 gr(GXm, 1);        // x_proj (MFMA, N=80 padded to one 128-tile)
                gemm_mfma<<<gr, blk, 0, stream>>>(xc, DI, xpw + (size_t)l*80*DI, DI,
                                                  nullptr, dbc, 80, nullptr, nullptr,
                                                  MG, 80, DI, 0);
            }
            {   dim3 gr(GXm, DI/128);   // dt_proj + softplus (MFMA, K=48 zero-padded)
                gemm_mfma<<<gr, blk, 0, stream>>>(dbc, 80, dtw + (size_t)l*DI*DTR, DTR,
                                                  nullptr, dtb, DI, dtbia + l*DI, nullptr,
                                                  MG, DI, DTR, 1);
            }
            scan_kernel<<<g*(DI/16), dim3(64), 0, stream>>>(dtb, xc, dbc,
                                                            Alog + (size_t)l*DI*DS,
                                                            Dpar + l*DI, ybuf);
            gate_ln<<<MG, blk, 0, stream>>>(ybuf, zh, snw + l*DI, snb + l*DI, gated);
            {   dim3 gr(GXm, DM/128);   // out_proj += residual (MFMA epi2)
                gemm_mfma<<<gr, blk, 0, stream>>>(gated, DI, opw + (size_t)l*DM*DI, DI,
                                                  residual + (size_t)b0*SEQ*DM, nullptr, DM,
                                                  nullptr, nullptr, MG, DM, DI, 2);
            }
        }
    }

    ln768<<<M_TOK, blk, 0, stream>>>(residual, nfw, nfb, hn);
    pool_kernel<<<(BATCH*DM)/256, blk, 0, stream>>>(hn, pooled);
    head_kernel<<<(BATCH*NCLS + 255)/256, blk, 0, stream>>>(flag, pooled, hw, hb, d_out);
}